// Round 2
// baseline (254.121 us; speedup 1.0000x reference)
//
#include <hip/hip_runtime.h>

#define LSEQ 2048
#define DIM 512
#define NH 8
#define HS 64

typedef __attribute__((ext_vector_type(8))) short short8;
typedef __attribute__((ext_vector_type(4))) float f32x4;

__device__ inline unsigned short f2bf(float f) {
  union { float f; unsigned u; } a; a.f = f;
  unsigned r = a.u + 0x7FFFu + ((a.u >> 16) & 1u);
  return (unsigned short)(r >> 16);
}
__device__ inline float bf2f(unsigned short h) {
  union { unsigned u; float f; } a; a.u = ((unsigned)h) << 16;
  return a.f;
}

__device__ inline f32x4 mfma_bf16(short8 a, short8 b, f32x4 c) {
  return __builtin_amdgcn_mfma_f32_16x16x32_bf16(a, b, c, 0, 0, 0);
}

__device__ inline short8 ld8(const unsigned short* p) {
  return *reinterpret_cast<const short8*>(p);
}

// ---------------- fused fp32 -> bf16 weight/Er convert ----------------
__global__ __launch_bounds__(256) void cvt_all_kernel(
    const float* __restrict__ wq, const float* __restrict__ wk,
    const float* __restrict__ wv, const float* __restrict__ wo,
    const float* __restrict__ Er,
    unsigned short* __restrict__ wqb, unsigned short* __restrict__ wkb,
    unsigned short* __restrict__ wvb, unsigned short* __restrict__ wob,
    unsigned short* __restrict__ erb) {
  int b = blockIdx.x;
  const float* src; unsigned short* dst; int off;
  if (b < 256)       { src = wq; dst = wqb; off = b; }
  else if (b < 512)  { src = wk; dst = wkb; off = b - 256; }
  else if (b < 768)  { src = wv; dst = wvb; off = b - 512; }
  else if (b < 1024) { src = wo; dst = wob; off = b - 768; }
  else               { src = Er; dst = erb; off = b - 1024; }
  int i = (off * 256 + threadIdx.x) * 4;
  float4 v = *reinterpret_cast<const float4*>(src + i);
  unsigned lo = (unsigned)f2bf(v.x) | ((unsigned)f2bf(v.y) << 16);
  unsigned hi = (unsigned)f2bf(v.z) | ((unsigned)f2bf(v.w) << 16);
  uint2 pk; pk.x = lo; pk.y = hi;
  *reinterpret_cast<uint2*>(dst + i) = pk;
}

// ---------------- LayerNorm: x (4096,512) f32 -> hn bf16 ----------------
__global__ __launch_bounds__(256) void ln_kernel(const float* __restrict__ x,
    const float* __restrict__ g, const float* __restrict__ bta,
    unsigned short* __restrict__ hn) {
  int row = blockIdx.x, tid = threadIdx.x;
  const float2* xr = reinterpret_cast<const float2*>(x + (size_t)row * DIM);
  float2 v = xr[tid];
  float s = v.x + v.y, sq = v.x * v.x + v.y * v.y;
#pragma unroll
  for (int off = 1; off < 64; off <<= 1) {
    s += __shfl_xor(s, off);
    sq += __shfl_xor(sq, off);
  }
  __shared__ float red[8];
  if ((tid & 63) == 0) { red[tid >> 6] = s; red[4 + (tid >> 6)] = sq; }
  __syncthreads();
  s = red[0] + red[1] + red[2] + red[3];
  sq = red[4] + red[5] + red[6] + red[7];
  float mu = s * (1.f / DIM);
  float var = sq * (1.f / DIM) - mu * mu;
  float rstd = rsqrtf(var + 1e-5f);
  float2 gg = reinterpret_cast<const float2*>(g)[tid];
  float2 bb = reinterpret_cast<const float2*>(bta)[tid];
  unsigned short h0 = f2bf((v.x - mu) * rstd * gg.x + bb.x);
  unsigned short h1 = f2bf((v.y - mu) * rstd * gg.y + bb.y);
  reinterpret_cast<unsigned int*>(hn)[(size_t)row * (DIM / 2) + tid] =
      (unsigned)h0 | ((unsigned)h1 << 16);
}

// ---------------- QKV projections ----------------
__global__ __launch_bounds__(256) void qkv_kernel(const unsigned short* __restrict__ hn,
    const unsigned short* __restrict__ wqb, const unsigned short* __restrict__ wkb,
    const unsigned short* __restrict__ wvb,
    const float* __restrict__ bq, const float* __restrict__ bk, const float* __restrict__ bv,
    unsigned short* __restrict__ qo, unsigned short* __restrict__ ko,
    unsigned short* __restrict__ vT) {
  int lane = threadIdx.x & 63, widx = threadIdx.x >> 6;
  int col = lane & 15, grp = lane >> 4;
  int wgid = blockIdx.x * 4 + widx;  // 0..6143
  int mat = wgid >> 11;
  int rem = wgid & 2047;
  int m0 = (rem >> 3) * 16;
  int n0 = (rem & 7) * 64;
  const unsigned short* W = (mat == 0) ? wqb : (mat == 1) ? wkb : wvb;
  const float* bias = (mat == 0) ? bq : (mat == 1) ? bk : bv;
  f32x4 acc[4];
#pragma unroll
  for (int i = 0; i < 4; ++i) acc[i] = (f32x4){0.f, 0.f, 0.f, 0.f};
  for (int k0 = 0; k0 < DIM; k0 += 32) {
    short8 af = ld8(hn + (size_t)(m0 + col) * DIM + k0 + 8 * grp);
#pragma unroll
    for (int nt = 0; nt < 4; ++nt) {
      short8 bf = ld8(W + (size_t)(n0 + nt * 16 + col) * DIM + k0 + 8 * grp);
      acc[nt] = mfma_bf16(af, bf, acc[nt]);
    }
  }
#pragma unroll
  for (int nt = 0; nt < 4; ++nt) {
    int n = n0 + nt * 16 + col;   // feature
    int hh = n >> 6, d = n & 63;
    float bsv = bias[n];
#pragma unroll
    for (int r = 0; r < 4; ++r) {
      int m = m0 + 4 * grp + r;   // token
      float val = acc[nt][r] + bsv;
      int b = m >> 11, l = m & (LSEQ - 1);
      unsigned short hv = f2bf(val);
      if (mat == 2)
        vT[((size_t)(b * NH + hh) * HS + d) * LSEQ + l] = hv;
      else {
        unsigned short* dst = (mat == 0) ? qo : ko;
        dst[((size_t)(b * NH + hh) * LSEQ + l) * HS + d] = hv;
      }
    }
  }
}

// ---------------- fused causal attention with skewed rel bias ----------------
// one wave per (16-row q-tile x <=512-key chunk); writes raw partial (O,m,l).
// 5120 wave-units total -> high occupancy; merged by merge_kernel.
__global__ __launch_bounds__(256, 4) void attn_kernel(const unsigned short* __restrict__ q,
    const unsigned short* __restrict__ k, const unsigned short* __restrict__ vT,
    const unsigned short* __restrict__ erb, char* __restrict__ partials) {
  __shared__ float Uall[4][80 * 18];
  int lane = threadIdx.x & 63, widx = threadIdx.x >> 6;
  int mcol = lane & 15, grp = lane >> 4;
  float* U = Uall[widx];
  int u = blockIdx.x * 4 + widx;  // 0..5119
  int bh = u / 320;
  int rem = u - bh * 320;
  int tile, chunk;
  if (rem < 32)       { tile = rem; chunk = 0; }
  else if (rem < 96)  { int idx = rem - 32;  tile = 32 + (idx >> 1); chunk = idx & 1; }
  else if (rem < 192) { int idx = rem - 96;  int t3 = idx / 3; tile = 64 + t3; chunk = idx - 3 * t3; }
  else                { int idx = rem - 192; tile = 96 + (idx >> 2); chunk = idx & 3; }
  int qi0 = tile << 4;
  int keys_total = qi0 + 16;
  int k_begin = chunk << 9;
  int k_end = min(k_begin + 512, keys_total);
  int nkb = (k_end - k_begin + 63) >> 6;
  int h = bh & 7;

  const unsigned short* Qb = q + (size_t)bh * LSEQ * HS;
  const unsigned short* Kb = k + (size_t)bh * LSEQ * HS;
  const unsigned short* Vb = vT + (size_t)bh * HS * LSEQ;
  const unsigned short* Eb = erb + (size_t)h * LSEQ * HS;

  short8 qf0 = ld8(Qb + (size_t)(qi0 + mcol) * HS + 8 * grp);
  short8 qf1 = ld8(Qb + (size_t)(qi0 + mcol) * HS + 32 + 8 * grp);
  f32x4 o[4];
#pragma unroll
  for (int i = 0; i < 4; ++i) o[i] = (f32x4){0.f, 0.f, 0.f, 0.f};
  float mrun = -3e38f, lsum = 0.f;

  for (int kb = 0; kb < nkb; ++kb) {
    int kj0 = k_begin + (kb << 6);
    // S^T: st[t][r] = K[kj0+16t+4g+r] . Q[qi0+mcol]
    f32x4 st[4];
#pragma unroll
    for (int t = 0; t < 4; ++t) {
      short8 kf0 = ld8(Kb + (size_t)(kj0 + 16 * t + mcol) * HS + 8 * grp);
      short8 kf1 = ld8(Kb + (size_t)(kj0 + 16 * t + mcol) * HS + 32 + 8 * grp);
      f32x4 a = (f32x4){0.f, 0.f, 0.f, 0.f};
      a = mfma_bf16(kf0, qf0, a);
      a = mfma_bf16(kf1, qf1, a);
      st[t] = a;
    }
    // rel-bias band: U[j][m] = Er[e0+j] . Q[qi0+m], j in [0,80), stride 18
    int e0 = 2032 - qi0 + kj0;
#pragma unroll
    for (int jt = 0; jt < 5; ++jt) {
      int er = e0 + 16 * jt + mcol;
      if (er > 2047) er = 2047;   // clamped rows only feed masked entries
      short8 ef0 = ld8(Eb + (size_t)er * HS + 8 * grp);
      short8 ef1 = ld8(Eb + (size_t)er * HS + 32 + 8 * grp);
      f32x4 uu = (f32x4){0.f, 0.f, 0.f, 0.f};
      uu = mfma_bf16(ef0, qf0, uu);
      uu = mfma_bf16(ef1, qf1, uu);
#pragma unroll
      for (int r = 0; r < 4; ++r)
        U[(16 * jt + 4 * grp + r) * 18 + mcol] = uu[r];
    }
    // logits + causal mask + skew gather rel[n][m] = U[n-m+15][m]
    float lt[4][4];
    float pmax = -3e38f;
#pragma unroll
    for (int t = 0; t < 4; ++t) {
#pragma unroll
      for (int r = 0; r < 4; ++r) {
        int n = 16 * t + 4 * grp + r;
        float val = st[t][r] * 0.125f + U[(n - mcol + 15) * 18 + mcol];
        if (kj0 + n > qi0 + mcol) val = -3e38f;
        lt[t][r] = val;
        pmax = fmaxf(pmax, val);
      }
    }
    pmax = fmaxf(pmax, __shfl_xor(pmax, 16));
    pmax = fmaxf(pmax, __shfl_xor(pmax, 32));
    float mnew = fmaxf(mrun, pmax);
    float alpha = __expf(mrun - mnew);
    float psum = 0.f;
#pragma unroll
    for (int t = 0; t < 4; ++t) {
#pragma unroll
      for (int r = 0; r < 4; ++r) {
        lt[t][r] = __expf(lt[t][r] - mnew);
        psum += lt[t][r];
      }
    }
    psum += __shfl_xor(psum, 16);
    psum += __shfl_xor(psum, 32);
    lsum = lsum * alpha + psum;
    mrun = mnew;
#pragma unroll
    for (int i = 0; i < 4; ++i) o[i] *= alpha;
    // pack P rows (key-major per lane) to bf16 pairs
    unsigned w0[4], w1[4];
#pragma unroll
    for (int t = 0; t < 4; ++t) {
      w0[t] = (unsigned)f2bf(lt[t][0]) | ((unsigned)f2bf(lt[t][1]) << 16);
      w1[t] = (unsigned)f2bf(lt[t][2]) | ((unsigned)f2bf(lt[t][3]) << 16);
    }
    // redistribute to B-fragment via shuffles: lane(mcol,grp) needs keys 32s+8grp..+7
    int srcA = mcol | ((grp & 1) << 5);
    int srcB = srcA + 16;
    bool hi = (grp >= 2);
#pragma unroll
    for (int s = 0; s < 2; ++s) {
      unsigned y0a = (unsigned)__shfl((int)w0[2 * s], srcA);
      unsigned y0b = (unsigned)__shfl((int)w0[2 * s + 1], srcA);
      unsigned y1a = (unsigned)__shfl((int)w1[2 * s], srcA);
      unsigned y1b = (unsigned)__shfl((int)w1[2 * s + 1], srcA);
      unsigned y2a = (unsigned)__shfl((int)w0[2 * s], srcB);
      unsigned y2b = (unsigned)__shfl((int)w0[2 * s + 1], srcB);
      unsigned y3a = (unsigned)__shfl((int)w1[2 * s], srcB);
      unsigned y3b = (unsigned)__shfl((int)w1[2 * s + 1], srcB);
      union { unsigned u4[4]; short8 s8; } pu;
      pu.u4[0] = hi ? y0b : y0a;
      pu.u4[1] = hi ? y1b : y1a;
      pu.u4[2] = hi ? y2b : y2a;
      pu.u4[3] = hi ? y3b : y3a;
#pragma unroll
      for (int dt = 0; dt < 4; ++dt) {
        short8 vf = ld8(Vb + (size_t)(dt * 16 + mcol) * LSEQ + kj0 + 32 * s + 8 * grp);
        o[dt] = mfma_bf16(vf, pu.s8, o[dt]);
      }
    }
  }
  // write raw partial: O (16x64 bf16), m[16], l[16]
  char* pb = partials + (size_t)u * 2176;
  unsigned* Ob = (unsigned*)pb;
#pragma unroll
  for (int dt = 0; dt < 4; ++dt) {
    unsigned a = (unsigned)f2bf(o[dt][0]) | ((unsigned)f2bf(o[dt][1]) << 16);
    unsigned b2 = (unsigned)f2bf(o[dt][2]) | ((unsigned)f2bf(o[dt][3]) << 16);
    Ob[mcol * 32 + dt * 8 + grp * 2] = a;
    Ob[mcol * 32 + dt * 8 + grp * 2 + 1] = b2;
  }
  if (grp == 0) {
    ((float*)(pb + 2048))[mcol] = mrun;
    ((float*)(pb + 2112))[mcol] = lsum;
  }
}

// ---------------- merge partials -> attT ----------------
__global__ __launch_bounds__(256) void merge_kernel(const char* __restrict__ partials,
    unsigned short* __restrict__ attT) {
  int lane = threadIdx.x & 63, widx = threadIdx.x >> 6;
  int tid = blockIdx.x * 4 + widx;  // 0..2047
  int bh = tid >> 7, i = tid & 127;
  int g = i >> 5;
  int start = 16 * g * (g + 1);
  int base_u = bh * 320 + start + (i & 31) * (g + 1);
  int nch = g + 1;
  int row = lane >> 2, d0 = (lane & 3) << 4;
  float M = -3e38f;
  for (int c = 0; c < nch; ++c) {
    const char* pb = partials + (size_t)(base_u + c) * 2176;
    M = fmaxf(M, ((const float*)(pb + 2048))[row]);
  }
  float acc[16];
#pragma unroll
  for (int j = 0; j < 16; ++j) acc[j] = 0.f;
  float lsum = 0.f;
  for (int c = 0; c < nch; ++c) {
    const char* pb = partials + (size_t)(base_u + c) * 2176;
    float mc = ((const float*)(pb + 2048))[row];
    float lc = ((const float*)(pb + 2112))[row];
    float s = __expf(mc - M);
    lsum += s * lc;
    short8 v0 = *reinterpret_cast<const short8*>(pb + row * 128 + d0 * 2);
    short8 v1 = *reinterpret_cast<const short8*>(pb + row * 128 + d0 * 2 + 16);
#pragma unroll
    for (int j = 0; j < 8; ++j) {
      acc[j]     += s * bf2f((unsigned short)v0[j]);
      acc[8 + j] += s * bf2f((unsigned short)v1[j]);
    }
  }
  float inv = 1.f / lsum;
  int b = bh >> 3, h = bh & 7;
  unsigned short* dst = attT + ((size_t)(b * LSEQ) + i * 16 + row) * DIM + h * HS + d0;
  union { unsigned short us[16]; short8 s8[2]; } ou;
#pragma unroll
  for (int j = 0; j < 16; ++j) ou.us[j] = f2bf(acc[j] * inv);
  *reinterpret_cast<short8*>(dst) = ou.s8[0];
  *reinterpret_cast<short8*>(dst + 8) = ou.s8[1];
}

// ---------------- output projection: attT @ wo^T + bo -> fp32 ----------------
__global__ __launch_bounds__(256) void out_kernel(const unsigned short* __restrict__ attT,
    const unsigned short* __restrict__ wob, const float* __restrict__ bo,
    float* __restrict__ out) {
  int lane = threadIdx.x & 63, widx = threadIdx.x >> 6;
  int col = lane & 15, grp = lane >> 4;
  int wgid = blockIdx.x * 4 + widx;  // 0..2047
  int m0 = (wgid >> 3) * 16;
  int n0 = (wgid & 7) * 64;
  f32x4 acc[4];
#pragma unroll
  for (int i = 0; i < 4; ++i) acc[i] = (f32x4){0.f, 0.f, 0.f, 0.f};
  for (int k0 = 0; k0 < DIM; k0 += 32) {
    short8 af = ld8(attT + (size_t)(m0 + col) * DIM + k0 + 8 * grp);
#pragma unroll
    for (int nt = 0; nt < 4; ++nt) {
      short8 bf = ld8(wob + (size_t)(n0 + nt * 16 + col) * DIM + k0 + 8 * grp);
      acc[nt] = mfma_bf16(af, bf, acc[nt]);
    }
  }
#pragma unroll
  for (int nt = 0; nt < 4; ++nt) {
    int n = n0 + nt * 16 + col;
    float bsv = bo[n];
#pragma unroll
    for (int r = 0; r < 4; ++r) {
      int m = m0 + 4 * grp + r;
      out[(size_t)m * DIM + n] = acc[nt][r] + bsv;
    }
  }
}

extern "C" void kernel_launch(void* const* d_in, const int* in_sizes, int n_in,
                              void* d_out, int out_size, void* d_ws, size_t ws_size,
                              hipStream_t stream) {
  const float* x    = (const float*)d_in[0];
  // d_in[1] = mask (causal triu, hardcoded)
  const float* ln_g = (const float*)d_in[2];
  const float* ln_b = (const float*)d_in[3];
  const float* wq   = (const float*)d_in[4];
  const float* bq   = (const float*)d_in[5];
  const float* wk   = (const float*)d_in[6];
  const float* bk   = (const float*)d_in[7];
  const float* wv   = (const float*)d_in[8];
  const float* bv   = (const float*)d_in[9];
  const float* wo   = (const float*)d_in[10];
  const float* bo   = (const float*)d_in[11];
  const float* Er   = (const float*)d_in[12];
  float* out = (float*)d_out;

  char* ws = (char*)d_ws;
  unsigned short* hn   = (unsigned short*)(ws);                    // 0..4 MiB
  unsigned short* qb   = (unsigned short*)(ws + (4u << 20));       // 4..8
  unsigned short* kb   = (unsigned short*)(ws + (8u << 20));       // 8..12
  unsigned short* vT   = (unsigned short*)(ws + (12u << 20));      // 12..16
  unsigned short* erb  = (unsigned short*)(ws + (16u << 20));      // 16..18
  unsigned short* attT = (unsigned short*)(ws + (18u << 20));      // 18..22
  unsigned short* wqb  = (unsigned short*)(ws + (22u << 20));      // 22..24
  unsigned short* wkb  = wqb + 512 * 512;
  unsigned short* wvb  = wkb + 512 * 512;
  unsigned short* wob  = wvb + 512 * 512;
  char* partials       = ws + (24u << 20);                         // 24..~34.7 MiB

  cvt_all_kernel<<<2048, 256, 0, stream>>>(wq, wk, wv, wo, Er, wqb, wkb, wvb, wob, erb);
  ln_kernel<<<4096, 256, 0, stream>>>(x, ln_g, ln_b, hn);
  qkv_kernel<<<1536, 256, 0, stream>>>(hn, wqb, wkb, wvb, bq, bk, bv, qb, kb, vT);
  attn_kernel<<<1280, 256, 0, stream>>>(qb, kb, vT, erb, partials);
  merge_kernel<<<512, 256, 0, stream>>>(partials, attT);
  out_kernel<<<512, 256, 0, stream>>>(attT, wob, bo, out);
}

// Round 3
// 252.012 us; speedup vs baseline: 1.0084x; 1.0084x over previous
//
#include <hip/hip_runtime.h>

#define LSEQ 2048
#define DIM 512
#define NH 8
#define HS 64

typedef __attribute__((ext_vector_type(8))) short short8;
typedef __attribute__((ext_vector_type(4))) float f32x4;

__device__ inline unsigned short f2bf(float f) {
  union { float f; unsigned u; } a; a.f = f;
  unsigned r = a.u + 0x7FFFu + ((a.u >> 16) & 1u);
  return (unsigned short)(r >> 16);
}
__device__ inline float bf2f(unsigned short h) {
  union { unsigned u; float f; } a; a.u = ((unsigned)h) << 16;
  return a.f;
}

__device__ inline f32x4 mfma_bf16(short8 a, short8 b, f32x4 c) {
  return __builtin_amdgcn_mfma_f32_16x16x32_bf16(a, b, c, 0, 0, 0);
}

__device__ inline short8 ld8(const unsigned short* p) {
  return *reinterpret_cast<const short8*>(p);
}

// ---------------- fused fp32 -> bf16 weight/Er convert ----------------
__global__ __launch_bounds__(256) void cvt_all_kernel(
    const float* __restrict__ wq, const float* __restrict__ wk,
    const float* __restrict__ wv, const float* __restrict__ wo,
    const float* __restrict__ Er,
    unsigned short* __restrict__ wqb, unsigned short* __restrict__ wkb,
    unsigned short* __restrict__ wvb, unsigned short* __restrict__ wob,
    unsigned short* __restrict__ erb) {
  int b = blockIdx.x;
  const float* src; unsigned short* dst; int off;
  if (b < 256)       { src = wq; dst = wqb; off = b; }
  else if (b < 512)  { src = wk; dst = wkb; off = b - 256; }
  else if (b < 768)  { src = wv; dst = wvb; off = b - 512; }
  else if (b < 1024) { src = wo; dst = wob; off = b - 768; }
  else               { src = Er; dst = erb; off = b - 1024; }
  int i = (off * 256 + threadIdx.x) * 4;
  float4 v = *reinterpret_cast<const float4*>(src + i);
  unsigned lo = (unsigned)f2bf(v.x) | ((unsigned)f2bf(v.y) << 16);
  unsigned hi = (unsigned)f2bf(v.z) | ((unsigned)f2bf(v.w) << 16);
  uint2 pk; pk.x = lo; pk.y = hi;
  *reinterpret_cast<uint2*>(dst + i) = pk;
}

// ---------------- LayerNorm: x (4096,512) f32 -> hn bf16 ----------------
__global__ __launch_bounds__(256) void ln_kernel(const float* __restrict__ x,
    const float* __restrict__ g, const float* __restrict__ bta,
    unsigned short* __restrict__ hn) {
  int row = blockIdx.x, tid = threadIdx.x;
  const float2* xr = reinterpret_cast<const float2*>(x + (size_t)row * DIM);
  float2 v = xr[tid];
  float s = v.x + v.y, sq = v.x * v.x + v.y * v.y;
#pragma unroll
  for (int off = 1; off < 64; off <<= 1) {
    s += __shfl_xor(s, off);
    sq += __shfl_xor(sq, off);
  }
  __shared__ float red[8];
  if ((tid & 63) == 0) { red[tid >> 6] = s; red[4 + (tid >> 6)] = sq; }
  __syncthreads();
  s = red[0] + red[1] + red[2] + red[3];
  sq = red[4] + red[5] + red[6] + red[7];
  float mu = s * (1.f / DIM);
  float var = sq * (1.f / DIM) - mu * mu;
  float rstd = rsqrtf(var + 1e-5f);
  float2 gg = reinterpret_cast<const float2*>(g)[tid];
  float2 bb = reinterpret_cast<const float2*>(bta)[tid];
  unsigned short h0 = f2bf((v.x - mu) * rstd * gg.x + bb.x);
  unsigned short h1 = f2bf((v.y - mu) * rstd * gg.y + bb.y);
  reinterpret_cast<unsigned int*>(hn)[(size_t)row * (DIM / 2) + tid] =
      (unsigned)h0 | ((unsigned)h1 << 16);
}

// ---------------- QKV projections ----------------
__global__ __launch_bounds__(256) void qkv_kernel(const unsigned short* __restrict__ hn,
    const unsigned short* __restrict__ wqb, const unsigned short* __restrict__ wkb,
    const unsigned short* __restrict__ wvb,
    const float* __restrict__ bq, const float* __restrict__ bk, const float* __restrict__ bv,
    unsigned short* __restrict__ qo, unsigned short* __restrict__ ko,
    unsigned short* __restrict__ vT) {
  int lane = threadIdx.x & 63, widx = threadIdx.x >> 6;
  int col = lane & 15, grp = lane >> 4;
  int wgid = blockIdx.x * 4 + widx;  // 0..6143
  int mat = wgid >> 11;
  int rem = wgid & 2047;
  int m0 = (rem >> 3) * 16;
  int n0 = (rem & 7) * 64;
  const unsigned short* W = (mat == 0) ? wqb : (mat == 1) ? wkb : wvb;
  const float* bias = (mat == 0) ? bq : (mat == 1) ? bk : bv;
  f32x4 acc[4];
#pragma unroll
  for (int i = 0; i < 4; ++i) acc[i] = (f32x4){0.f, 0.f, 0.f, 0.f};
  for (int k0 = 0; k0 < DIM; k0 += 32) {
    short8 af = ld8(hn + (size_t)(m0 + col) * DIM + k0 + 8 * grp);
#pragma unroll
    for (int nt = 0; nt < 4; ++nt) {
      short8 bf = ld8(W + (size_t)(n0 + nt * 16 + col) * DIM + k0 + 8 * grp);
      acc[nt] = mfma_bf16(af, bf, acc[nt]);
    }
  }
#pragma unroll
  for (int nt = 0; nt < 4; ++nt) {
    int n = n0 + nt * 16 + col;   // feature
    int hh = n >> 6, d = n & 63;
    float bsv = bias[n];
#pragma unroll
    for (int r = 0; r < 4; ++r) {
      int m = m0 + 4 * grp + r;   // token
      float val = acc[nt][r] + bsv;
      int b = m >> 11, l = m & (LSEQ - 1);
      unsigned short hv = f2bf(val);
      if (mat == 2)
        vT[((size_t)(b * NH + hh) * HS + d) * LSEQ + l] = hv;
      else {
        unsigned short* dst = (mat == 0) ? qo : ko;
        dst[((size_t)(b * NH + hh) * LSEQ + l) * HS + d] = hv;
      }
    }
  }
}

// ---------------- fused causal attention with skewed rel bias ----------------
// one wave per (16-row q-tile x <=512-key chunk); writes raw partial (O,m,l).
// XCD-pinned: all blocks of a (b,h) land on one XCD so K/V/Er stay L2-resident.
__global__ __launch_bounds__(256, 4) void attn_kernel(const unsigned short* __restrict__ q,
    const unsigned short* __restrict__ k, const unsigned short* __restrict__ vT,
    const unsigned short* __restrict__ erb, char* __restrict__ partials) {
  __shared__ float Uall[4][80 * 18];
  int lane = threadIdx.x & 63, widx = threadIdx.x >> 6;
  int mcol = lane & 15, grp = lane >> 4;
  float* U = Uall[widx];
  // XCD-affinity mapping: xcd = blockIdx & 7 (round-robin); 2 bh per XCD.
  int xcd = blockIdx.x & 7;
  int i = blockIdx.x >> 3;           // 0..159
  int hi2 = (i >= 80) ? 1 : 0;
  int bh = xcd + 8 * hi2;            // 0..15
  int local = i - 80 * hi2;          // 0..79 block within bh
  int rem = local * 4 + widx;        // 0..319 wave-unit within bh
  int u = bh * 320 + rem;            // global unit id for partials
  int tile, chunk;
  if (rem < 32)       { tile = rem; chunk = 0; }
  else if (rem < 96)  { int idx = rem - 32;  tile = 32 + (idx >> 1); chunk = idx & 1; }
  else if (rem < 192) { int idx = rem - 96;  int t3 = idx / 3; tile = 64 + t3; chunk = idx - 3 * t3; }
  else                { int idx = rem - 192; tile = 96 + (idx >> 2); chunk = idx & 3; }
  int qi0 = tile << 4;
  int keys_total = qi0 + 16;
  int k_begin = chunk << 9;
  int k_end = min(k_begin + 512, keys_total);
  int nkb = (k_end - k_begin + 63) >> 6;
  int h = bh & 7;

  const unsigned short* Qb = q + (size_t)bh * LSEQ * HS;
  const unsigned short* Kb = k + (size_t)bh * LSEQ * HS;
  const unsigned short* Vb = vT + (size_t)bh * HS * LSEQ;
  const unsigned short* Eb = erb + (size_t)h * LSEQ * HS;

  short8 qf0 = ld8(Qb + (size_t)(qi0 + mcol) * HS + 8 * grp);
  short8 qf1 = ld8(Qb + (size_t)(qi0 + mcol) * HS + 32 + 8 * grp);
  f32x4 o[4];
#pragma unroll
  for (int i2 = 0; i2 < 4; ++i2) o[i2] = (f32x4){0.f, 0.f, 0.f, 0.f};
  float mrun = -3e38f, lsum = 0.f;

  for (int kb = 0; kb < nkb; ++kb) {
    int kj0 = k_begin + (kb << 6);
    // S^T: st[t][r] = K[kj0+16t+4g+r] . Q[qi0+mcol]
    f32x4 st[4];
#pragma unroll
    for (int t = 0; t < 4; ++t) {
      short8 kf0 = ld8(Kb + (size_t)(kj0 + 16 * t + mcol) * HS + 8 * grp);
      short8 kf1 = ld8(Kb + (size_t)(kj0 + 16 * t + mcol) * HS + 32 + 8 * grp);
      f32x4 a = (f32x4){0.f, 0.f, 0.f, 0.f};
      a = mfma_bf16(kf0, qf0, a);
      a = mfma_bf16(kf1, qf1, a);
      st[t] = a;
    }
    // rel-bias band: U[j][m] = Er[e0+j] . Q[qi0+m], j in [0,80), stride 18
    int e0 = 2032 - qi0 + kj0;
#pragma unroll
    for (int jt = 0; jt < 5; ++jt) {
      int er = e0 + 16 * jt + mcol;
      if (er > 2047) er = 2047;   // clamped rows only feed masked entries
      short8 ef0 = ld8(Eb + (size_t)er * HS + 8 * grp);
      short8 ef1 = ld8(Eb + (size_t)er * HS + 32 + 8 * grp);
      f32x4 uu = (f32x4){0.f, 0.f, 0.f, 0.f};
      uu = mfma_bf16(ef0, qf0, uu);
      uu = mfma_bf16(ef1, qf1, uu);
#pragma unroll
      for (int r = 0; r < 4; ++r)
        U[(16 * jt + 4 * grp + r) * 18 + mcol] = uu[r];
    }
    // logits + causal mask + skew gather rel[n][m] = U[n-m+15][m]
    float lt[4][4];
    float pmax = -3e38f;
#pragma unroll
    for (int t = 0; t < 4; ++t) {
#pragma unroll
      for (int r = 0; r < 4; ++r) {
        int n = 16 * t + 4 * grp + r;
        float val = st[t][r] * 0.125f + U[(n - mcol + 15) * 18 + mcol];
        if (kj0 + n > qi0 + mcol) val = -3e38f;
        lt[t][r] = val;
        pmax = fmaxf(pmax, val);
      }
    }
    pmax = fmaxf(pmax, __shfl_xor(pmax, 16));
    pmax = fmaxf(pmax, __shfl_xor(pmax, 32));
    float mnew = fmaxf(mrun, pmax);
    float alpha = __expf(mrun - mnew);
    float psum = 0.f;
#pragma unroll
    for (int t = 0; t < 4; ++t) {
#pragma unroll
      for (int r = 0; r < 4; ++r) {
        lt[t][r] = __expf(lt[t][r] - mnew);
        psum += lt[t][r];
      }
    }
    psum += __shfl_xor(psum, 16);
    psum += __shfl_xor(psum, 32);
    lsum = lsum * alpha + psum;
    mrun = mnew;
#pragma unroll
    for (int i2 = 0; i2 < 4; ++i2) o[i2] *= alpha;
    // pack P rows (key-major per lane) to bf16 pairs
    unsigned w0[4], w1[4];
#pragma unroll
    for (int t = 0; t < 4; ++t) {
      w0[t] = (unsigned)f2bf(lt[t][0]) | ((unsigned)f2bf(lt[t][1]) << 16);
      w1[t] = (unsigned)f2bf(lt[t][2]) | ((unsigned)f2bf(lt[t][3]) << 16);
    }
    // redistribute to B-fragment via shuffles: lane(mcol,grp) needs keys 32s+8grp..+7
    int srcA = mcol | ((grp & 1) << 5);
    int srcB = srcA + 16;
    bool hi = (grp >= 2);
#pragma unroll
    for (int s = 0; s < 2; ++s) {
      unsigned y0a = (unsigned)__shfl((int)w0[2 * s], srcA);
      unsigned y0b = (unsigned)__shfl((int)w0[2 * s + 1], srcA);
      unsigned y1a = (unsigned)__shfl((int)w1[2 * s], srcA);
      unsigned y1b = (unsigned)__shfl((int)w1[2 * s + 1], srcA);
      unsigned y2a = (unsigned)__shfl((int)w0[2 * s], srcB);
      unsigned y2b = (unsigned)__shfl((int)w0[2 * s + 1], srcB);
      unsigned y3a = (unsigned)__shfl((int)w1[2 * s], srcB);
      unsigned y3b = (unsigned)__shfl((int)w1[2 * s + 1], srcB);
      union { unsigned u4[4]; short8 s8; } pu;
      pu.u4[0] = hi ? y0b : y0a;
      pu.u4[1] = hi ? y1b : y1a;
      pu.u4[2] = hi ? y2b : y2a;
      pu.u4[3] = hi ? y3b : y3a;
#pragma unroll
      for (int dt = 0; dt < 4; ++dt) {
        short8 vf = ld8(Vb + (size_t)(dt * 16 + mcol) * LSEQ + kj0 + 32 * s + 8 * grp);
        o[dt] = mfma_bf16(vf, pu.s8, o[dt]);
      }
    }
  }
  // write raw partial: O (16x64 bf16), m[16], l[16]
  char* pb = partials + (size_t)u * 2176;
  unsigned* Ob = (unsigned*)pb;
#pragma unroll
  for (int dt = 0; dt < 4; ++dt) {
    unsigned a = (unsigned)f2bf(o[dt][0]) | ((unsigned)f2bf(o[dt][1]) << 16);
    unsigned b2 = (unsigned)f2bf(o[dt][2]) | ((unsigned)f2bf(o[dt][3]) << 16);
    Ob[mcol * 32 + dt * 8 + grp * 2] = a;
    Ob[mcol * 32 + dt * 8 + grp * 2 + 1] = b2;
  }
  if (grp == 0) {
    ((float*)(pb + 2048))[mcol] = mrun;
    ((float*)(pb + 2112))[mcol] = lsum;
  }
}

// ---------------- merge partials -> attT ----------------
__global__ __launch_bounds__(256) void merge_kernel(const char* __restrict__ partials,
    unsigned short* __restrict__ attT) {
  int lane = threadIdx.x & 63, widx = threadIdx.x >> 6;
  int tid = blockIdx.x * 4 + widx;  // 0..2047
  int bh = tid >> 7, i = tid & 127;
  int g = i >> 5;
  int start = 16 * g * (g + 1);
  int base_u = bh * 320 + start + (i & 31) * (g + 1);
  int nch = g + 1;
  int row = lane >> 2, d0 = (lane & 3) << 4;
  float M = -3e38f;
  for (int c = 0; c < nch; ++c) {
    const char* pb = partials + (size_t)(base_u + c) * 2176;
    M = fmaxf(M, ((const float*)(pb + 2048))[row]);
  }
  float acc[16];
#pragma unroll
  for (int j = 0; j < 16; ++j) acc[j] = 0.f;
  float lsum = 0.f;
  for (int c = 0; c < nch; ++c) {
    const char* pb = partials + (size_t)(base_u + c) * 2176;
    float mc = ((const float*)(pb + 2048))[row];
    float lc = ((const float*)(pb + 2112))[row];
    float s = __expf(mc - M);
    lsum += s * lc;
    short8 v0 = *reinterpret_cast<const short8*>(pb + row * 128 + d0 * 2);
    short8 v1 = *reinterpret_cast<const short8*>(pb + row * 128 + d0 * 2 + 16);
#pragma unroll
    for (int j = 0; j < 8; ++j) {
      acc[j]     += s * bf2f((unsigned short)v0[j]);
      acc[8 + j] += s * bf2f((unsigned short)v1[j]);
    }
  }
  float inv = 1.f / lsum;
  int b = bh >> 3, h = bh & 7;
  unsigned short* dst = attT + ((size_t)(b * LSEQ) + i * 16 + row) * DIM + h * HS + d0;
  union { unsigned short us[16]; short8 s8[2]; } ou;
#pragma unroll
  for (int j = 0; j < 16; ++j) ou.us[j] = f2bf(acc[j] * inv);
  *reinterpret_cast<short8*>(dst) = ou.s8[0];
  *reinterpret_cast<short8*>(dst + 8) = ou.s8[1];
}

// ---------------- output projection: attT @ wo^T + bo -> fp32 ----------------
__global__ __launch_bounds__(256) void out_kernel(const unsigned short* __restrict__ attT,
    const unsigned short* __restrict__ wob, const float* __restrict__ bo,
    float* __restrict__ out) {
  int lane = threadIdx.x & 63, widx = threadIdx.x >> 6;
  int col = lane & 15, grp = lane >> 4;
  int wgid = blockIdx.x * 4 + widx;  // 0..2047
  int m0 = (wgid >> 3) * 16;
  int n0 = (wgid & 7) * 64;
  f32x4 acc[4];
#pragma unroll
  for (int i = 0; i < 4; ++i) acc[i] = (f32x4){0.f, 0.f, 0.f, 0.f};
  for (int k0 = 0; k0 < DIM; k0 += 32) {
    short8 af = ld8(attT + (size_t)(m0 + col) * DIM + k0 + 8 * grp);
#pragma unroll
    for (int nt = 0; nt < 4; ++nt) {
      short8 bf = ld8(wob + (size_t)(n0 + nt * 16 + col) * DIM + k0 + 8 * grp);
      acc[nt] = mfma_bf16(af, bf, acc[nt]);
    }
  }
#pragma unroll
  for (int nt = 0; nt < 4; ++nt) {
    int n = n0 + nt * 16 + col;
    float bsv = bo[n];
#pragma unroll
    for (int r = 0; r < 4; ++r) {
      int m = m0 + 4 * grp + r;
      out[(size_t)m * DIM + n] = acc[nt][r] + bsv;
    }
  }
}

extern "C" void kernel_launch(void* const* d_in, const int* in_sizes, int n_in,
                              void* d_out, int out_size, void* d_ws, size_t ws_size,
                              hipStream_t stream) {
  const float* x    = (const float*)d_in[0];
  // d_in[1] = mask (causal triu, hardcoded)
  const float* ln_g = (const float*)d_in[2];
  const float* ln_b = (const float*)d_in[3];
  const float* wq   = (const float*)d_in[4];
  const float* bq   = (const float*)d_in[5];
  const float* wk   = (const float*)d_in[6];
  const float* bk   = (const float*)d_in[7];
  const float* wv   = (const float*)d_in[8];
  const float* bv   = (const float*)d_in[9];
  const float* wo   = (const float*)d_in[10];
  const float* bo   = (const float*)d_in[11];
  const float* Er   = (const float*)d_in[12];
  float* out = (float*)d_out;

  char* ws = (char*)d_ws;
  unsigned short* hn   = (unsigned short*)(ws);                    // 0..4 MiB
  unsigned short* qb   = (unsigned short*)(ws + (4u << 20));       // 4..8
  unsigned short* kb   = (unsigned short*)(ws + (8u << 20));       // 8..12
  unsigned short* vT   = (unsigned short*)(ws + (12u << 20));      // 12..16
  unsigned short* erb  = (unsigned short*)(ws + (16u << 20));      // 16..18
  unsigned short* attT = (unsigned short*)(ws + (18u << 20));      // 18..22
  unsigned short* wqb  = (unsigned short*)(ws + (22u << 20));      // 22..24
  unsigned short* wkb  = wqb + 512 * 512;
  unsigned short* wvb  = wkb + 512 * 512;
  unsigned short* wob  = wvb + 512 * 512;
  char* partials       = ws + (24u << 20);                         // 24..~34.7 MiB

  cvt_all_kernel<<<2048, 256, 0, stream>>>(wq, wk, wv, wo, Er, wqb, wkb, wvb, wob, erb);
  ln_kernel<<<4096, 256, 0, stream>>>(x, ln_g, ln_b, hn);
  qkv_kernel<<<1536, 256, 0, stream>>>(hn, wqb, wkb, wvb, bq, bk, bv, qb, kb, vT);
  attn_kernel<<<1280, 256, 0, stream>>>(qb, kb, vT, erb, partials);
  merge_kernel<<<512, 256, 0, stream>>>(partials, attT);
  out_kernel<<<512, 256, 0, stream>>>(attT, wob, bo, out);
}

// Round 4
// 210.300 us; speedup vs baseline: 1.2084x; 1.1983x over previous
//
#include <hip/hip_runtime.h>

#define LSEQ 2048
#define DIM 512
#define NH 8
#define HS 64

typedef __attribute__((ext_vector_type(8))) short short8;
typedef __attribute__((ext_vector_type(4))) float f32x4;

__device__ inline unsigned short f2bf(float f) {
  union { float f; unsigned u; } a; a.f = f;
  unsigned r = a.u + 0x7FFFu + ((a.u >> 16) & 1u);
  return (unsigned short)(r >> 16);
}
__device__ inline float bf2f(unsigned short h) {
  union { unsigned u; float f; } a; a.u = ((unsigned)h) << 16;
  return a.f;
}

__device__ inline f32x4 mfma_bf16(short8 a, short8 b, f32x4 c) {
  return __builtin_amdgcn_mfma_f32_16x16x32_bf16(a, b, c, 0, 0, 0);
}

__device__ inline short8 ld8(const unsigned short* p) {
  return *reinterpret_cast<const short8*>(p);
}

// ---------------- fused fp32 -> bf16 weight/Er convert ----------------
__global__ __launch_bounds__(256) void cvt_all_kernel(
    const float* __restrict__ wq, const float* __restrict__ wk,
    const float* __restrict__ wv, const float* __restrict__ wo,
    const float* __restrict__ Er,
    unsigned short* __restrict__ wqb, unsigned short* __restrict__ wkb,
    unsigned short* __restrict__ wvb, unsigned short* __restrict__ wob,
    unsigned short* __restrict__ erb) {
  int b = blockIdx.x;
  const float* src; unsigned short* dst; int off;
  if (b < 256)       { src = wq; dst = wqb; off = b; }
  else if (b < 512)  { src = wk; dst = wkb; off = b - 256; }
  else if (b < 768)  { src = wv; dst = wvb; off = b - 512; }
  else if (b < 1024) { src = wo; dst = wob; off = b - 768; }
  else               { src = Er; dst = erb; off = b - 1024; }
  int i = (off * 256 + threadIdx.x) * 4;
  float4 v = *reinterpret_cast<const float4*>(src + i);
  unsigned lo = (unsigned)f2bf(v.x) | ((unsigned)f2bf(v.y) << 16);
  unsigned hi = (unsigned)f2bf(v.z) | ((unsigned)f2bf(v.w) << 16);
  uint2 pk; pk.x = lo; pk.y = hi;
  *reinterpret_cast<uint2*>(dst + i) = pk;
}

// ---------------- LayerNorm: x (4096,512) f32 -> hn bf16 ----------------
__global__ __launch_bounds__(256) void ln_kernel(const float* __restrict__ x,
    const float* __restrict__ g, const float* __restrict__ bta,
    unsigned short* __restrict__ hn) {
  int row = blockIdx.x, tid = threadIdx.x;
  const float2* xr = reinterpret_cast<const float2*>(x + (size_t)row * DIM);
  float2 v = xr[tid];
  float s = v.x + v.y, sq = v.x * v.x + v.y * v.y;
#pragma unroll
  for (int off = 1; off < 64; off <<= 1) {
    s += __shfl_xor(s, off);
    sq += __shfl_xor(sq, off);
  }
  __shared__ float red[8];
  if ((tid & 63) == 0) { red[tid >> 6] = s; red[4 + (tid >> 6)] = sq; }
  __syncthreads();
  s = red[0] + red[1] + red[2] + red[3];
  sq = red[4] + red[5] + red[6] + red[7];
  float mu = s * (1.f / DIM);
  float var = sq * (1.f / DIM) - mu * mu;
  float rstd = rsqrtf(var + 1e-5f);
  float2 gg = reinterpret_cast<const float2*>(g)[tid];
  float2 bb = reinterpret_cast<const float2*>(bta)[tid];
  unsigned short h0 = f2bf((v.x - mu) * rstd * gg.x + bb.x);
  unsigned short h1 = f2bf((v.y - mu) * rstd * gg.y + bb.y);
  reinterpret_cast<unsigned int*>(hn)[(size_t)row * (DIM / 2) + tid] =
      (unsigned)h0 | ((unsigned)h1 << 16);
}

// ---------------- QKV projections ----------------
__global__ __launch_bounds__(256) void qkv_kernel(const unsigned short* __restrict__ hn,
    const unsigned short* __restrict__ wqb, const unsigned short* __restrict__ wkb,
    const unsigned short* __restrict__ wvb,
    const float* __restrict__ bq, const float* __restrict__ bk, const float* __restrict__ bv,
    unsigned short* __restrict__ qo, unsigned short* __restrict__ ko,
    unsigned short* __restrict__ vT) {
  int lane = threadIdx.x & 63, widx = threadIdx.x >> 6;
  int col = lane & 15, grp = lane >> 4;
  int wgid = blockIdx.x * 4 + widx;  // 0..6143
  int mat = wgid >> 11;
  int rem = wgid & 2047;
  int m0 = (rem >> 3) * 16;
  int n0 = (rem & 7) * 64;
  const unsigned short* W = (mat == 0) ? wqb : (mat == 1) ? wkb : wvb;
  const float* bias = (mat == 0) ? bq : (mat == 1) ? bk : bv;
  f32x4 acc[4];
#pragma unroll
  for (int i = 0; i < 4; ++i) acc[i] = (f32x4){0.f, 0.f, 0.f, 0.f};
  for (int k0 = 0; k0 < DIM; k0 += 32) {
    short8 af = ld8(hn + (size_t)(m0 + col) * DIM + k0 + 8 * grp);
#pragma unroll
    for (int nt = 0; nt < 4; ++nt) {
      short8 bf = ld8(W + (size_t)(n0 + nt * 16 + col) * DIM + k0 + 8 * grp);
      acc[nt] = mfma_bf16(af, bf, acc[nt]);
    }
  }
#pragma unroll
  for (int nt = 0; nt < 4; ++nt) {
    int n = n0 + nt * 16 + col;   // feature
    int hh = n >> 6, d = n & 63;
    float bsv = bias[n];
#pragma unroll
    for (int r = 0; r < 4; ++r) {
      int m = m0 + 4 * grp + r;   // token
      float val = acc[nt][r] + bsv;
      int b = m >> 11, l = m & (LSEQ - 1);
      unsigned short hv = f2bf(val);
      if (mat == 2)
        vT[((size_t)(b * NH + hh) * HS + d) * LSEQ + l] = hv;
      else {
        unsigned short* dst = (mat == 0) ? qo : ko;
        dst[((size_t)(b * NH + hh) * LSEQ + l) * HS + d] = hv;
      }
    }
  }
}

// ---------------- fused causal attention with skewed rel bias ----------------
// Cooperative block: 4 waves share one (bh, 16-row q-tile, 256-key chunk).
// Shared U band (272 rows) computed once per block; wave w handles keys
// [c0+64w, c0+64w+64); single softmax per wave; in-block 4->1 merge -> partial.
__global__ __launch_bounds__(256, 4) void attn_kernel(const unsigned short* __restrict__ q,
    const unsigned short* __restrict__ k, const unsigned short* __restrict__ vT,
    const unsigned short* __restrict__ erb, char* __restrict__ partials) {
  __shared__ float U[272 * 18];        // 19.6 KB shared rel-bias band
  __shared__ unsigned OB[4][512];      // per-wave O, bf16-packed
  __shared__ float MB[4][16];
  __shared__ float LB[4][16];
  int tid = threadIdx.x;
  int lane = tid & 63, w = tid >> 6, mcol = lane & 15, grp = lane >> 4;
  // XCD pinning + heavy-first ordering
  int bid = blockIdx.x;
  int xcd = bid & 7, s = bid >> 3;          // s in [0,1152)
  int hi2 = (s >= 576) ? 1 : 0;
  int bh = xcd + 8 * hi2;
  int lu = 575 - (s - 576 * hi2);           // heavy chunks first
  int g = 0;
#pragma unroll
  for (int t = 1; t < 8; ++t) if (8 * t * (t + 1) <= lu) g = t;
  int idx = lu - 8 * g * (g + 1);
  int qd = idx / (g + 1);
  int tile = 16 * g + qd;
  int chunk = idx - qd * (g + 1);
  int qi0 = tile << 4;
  int c0 = chunk << 8;
  int kend = min(c0 + 256, qi0 + 16);
  int h = bh & 7;

  const unsigned short* Qb = q + (size_t)bh * LSEQ * HS;
  const unsigned short* Kb = k + (size_t)bh * LSEQ * HS;
  const unsigned short* Vb = vT + (size_t)bh * HS * LSEQ;
  const unsigned short* Eb = erb + (size_t)h * LSEQ * HS;

  short8 qf0 = ld8(Qb + (size_t)(qi0 + mcol) * HS + 8 * grp);
  short8 qf1 = ld8(Qb + (size_t)(qi0 + mcol) * HS + 32 + 8 * grp);

  int kj0 = c0 + (w << 6);
  bool active = kj0 < kend;
  // K loads (clamped rows; masked later)
  short8 kf[8];
#pragma unroll
  for (int t = 0; t < 4; ++t) {
    int row = min(kj0 + 16 * t + mcol, 2047);
    kf[2 * t]     = ld8(Kb + (size_t)row * HS + 8 * grp);
    kf[2 * t + 1] = ld8(Kb + (size_t)row * HS + 32 + 8 * grp);
  }
  // shared U band: 17 16-row blocks over 4 waves
  int e0 = 2032 - qi0 + c0;   // >= 0
#pragma unroll
  for (int pi = 0; pi < 5; ++pi) {
    int j16 = w + 4 * pi;
    if (j16 <= 16) {
      int jr = j16 << 4;
      int er = min(e0 + jr + mcol, 2047);
      short8 ef0 = ld8(Eb + (size_t)er * HS + 8 * grp);
      short8 ef1 = ld8(Eb + (size_t)er * HS + 32 + 8 * grp);
      f32x4 uu = (f32x4){0.f, 0.f, 0.f, 0.f};
      uu = mfma_bf16(ef0, qf0, uu);
      uu = mfma_bf16(ef1, qf1, uu);
#pragma unroll
      for (int r = 0; r < 4; ++r)
        U[(jr + 4 * grp + r) * 18 + mcol] = uu[r];
    }
  }
  __syncthreads();
  // score S^T: st[t][r] = K[kj0+16t+4g+r] . Q[qi0+mcol]
  f32x4 st[4];
#pragma unroll
  for (int t = 0; t < 4; ++t) {
    f32x4 a = (f32x4){0.f, 0.f, 0.f, 0.f};
    a = mfma_bf16(kf[2 * t], qf0, a);
    a = mfma_bf16(kf[2 * t + 1], qf1, a);
    st[t] = a;
  }
  // V loads issued now (land during softmax/pack)
  short8 vf[8];
  int kv0 = min(kj0, LSEQ - 64);
#pragma unroll
  for (int s2 = 0; s2 < 2; ++s2)
#pragma unroll
    for (int dt = 0; dt < 4; ++dt)
      vf[s2 * 4 + dt] = ld8(Vb + (size_t)(dt * 16 + mcol) * LSEQ + kv0 + 32 * s2 + 8 * grp);
  // logits + causal mask + skew gather
  float lt[4][4];
  float pmax = -3e38f;
#pragma unroll
  for (int t = 0; t < 4; ++t) {
#pragma unroll
    for (int r = 0; r < 4; ++r) {
      int n = 16 * t + 4 * grp + r;
      int jrel = (w << 6) + n - mcol + 15;
      float val = st[t][r] * 0.125f + U[jrel * 18 + mcol];
      if (kj0 + n > qi0 + mcol) val = -3e38f;
      lt[t][r] = val;
      pmax = fmaxf(pmax, val);
    }
  }
  pmax = fmaxf(pmax, __shfl_xor(pmax, 16));
  pmax = fmaxf(pmax, __shfl_xor(pmax, 32));
  float kill = active ? 1.f : 0.f;
  float psum = 0.f;
#pragma unroll
  for (int t = 0; t < 4; ++t) {
#pragma unroll
    for (int r = 0; r < 4; ++r) {
      lt[t][r] = __expf(lt[t][r] - pmax) * kill;
      psum += lt[t][r];
    }
  }
  psum += __shfl_xor(psum, 16);
  psum += __shfl_xor(psum, 32);
  // pack P rows to bf16 pairs
  unsigned w0[4], w1[4];
#pragma unroll
  for (int t = 0; t < 4; ++t) {
    w0[t] = (unsigned)f2bf(lt[t][0]) | ((unsigned)f2bf(lt[t][1]) << 16);
    w1[t] = (unsigned)f2bf(lt[t][2]) | ((unsigned)f2bf(lt[t][3]) << 16);
  }
  // redistribute to B-fragment via shuffles
  int srcA = mcol | ((grp & 1) << 5);
  int srcB = srcA + 16;
  bool hi = (grp >= 2);
  f32x4 o[4];
#pragma unroll
  for (int i2 = 0; i2 < 4; ++i2) o[i2] = (f32x4){0.f, 0.f, 0.f, 0.f};
#pragma unroll
  for (int s2 = 0; s2 < 2; ++s2) {
    unsigned y0a = (unsigned)__shfl((int)w0[2 * s2], srcA);
    unsigned y0b = (unsigned)__shfl((int)w0[2 * s2 + 1], srcA);
    unsigned y1a = (unsigned)__shfl((int)w1[2 * s2], srcA);
    unsigned y1b = (unsigned)__shfl((int)w1[2 * s2 + 1], srcA);
    unsigned y2a = (unsigned)__shfl((int)w0[2 * s2], srcB);
    unsigned y2b = (unsigned)__shfl((int)w0[2 * s2 + 1], srcB);
    unsigned y3a = (unsigned)__shfl((int)w1[2 * s2], srcB);
    unsigned y3b = (unsigned)__shfl((int)w1[2 * s2 + 1], srcB);
    union { unsigned u4[4]; short8 s8; } pu;
    pu.u4[0] = hi ? y0b : y0a;
    pu.u4[1] = hi ? y1b : y1a;
    pu.u4[2] = hi ? y2b : y2a;
    pu.u4[3] = hi ? y3b : y3a;
#pragma unroll
    for (int dt = 0; dt < 4; ++dt)
      o[dt] = mfma_bf16(vf[s2 * 4 + dt], pu.s8, o[dt]);
  }
  // per-wave result -> LDS
#pragma unroll
  for (int dt = 0; dt < 4; ++dt) {
    OB[w][mcol * 32 + dt * 8 + grp * 2]     = (unsigned)f2bf(o[dt][0]) | ((unsigned)f2bf(o[dt][1]) << 16);
    OB[w][mcol * 32 + dt * 8 + grp * 2 + 1] = (unsigned)f2bf(o[dt][2]) | ((unsigned)f2bf(o[dt][3]) << 16);
  }
  if (grp == 0) {
    MB[w][mcol] = active ? pmax : -3e38f;
    LB[w][mcol] = psum;
  }
  __syncthreads();
  // in-block 4->1 merge: thread (row, dg) handles 4 d-values
  int row = tid >> 4, dg = tid & 15;
  float M = fmaxf(fmaxf(MB[0][row], MB[1][row]), fmaxf(MB[2][row], MB[3][row]));
  float acc0 = 0.f, acc1 = 0.f, acc2 = 0.f, acc3 = 0.f, lsum = 0.f;
#pragma unroll
  for (int w2 = 0; w2 < 4; ++w2) {
    float mw = MB[w2][row];
    float sw = __expf(mw - M);
    lsum += sw * LB[w2][row];
    unsigned u0 = OB[w2][row * 32 + dg * 2];
    unsigned u1 = OB[w2][row * 32 + dg * 2 + 1];
    acc0 += sw * bf2f((unsigned short)(u0 & 0xFFFF));
    acc1 += sw * bf2f((unsigned short)(u0 >> 16));
    acc2 += sw * bf2f((unsigned short)(u1 & 0xFFFF));
    acc3 += sw * bf2f((unsigned short)(u1 >> 16));
  }
  int u = bh * 576 + lu;
  char* pb = partials + (size_t)u * 2176;
  unsigned* Ob = (unsigned*)pb;
  Ob[row * 32 + dg * 2]     = (unsigned)f2bf(acc0) | ((unsigned)f2bf(acc1) << 16);
  Ob[row * 32 + dg * 2 + 1] = (unsigned)f2bf(acc2) | ((unsigned)f2bf(acc3) << 16);
  if (dg == 0) {
    ((float*)(pb + 2048))[row] = M;
    ((float*)(pb + 2112))[row] = lsum;
  }
}

// ---------------- merge partials -> attT ----------------
__global__ __launch_bounds__(256) void merge_kernel(const char* __restrict__ partials,
    unsigned short* __restrict__ attT) {
  int lane = threadIdx.x & 63, widx = threadIdx.x >> 6;
  int tid = blockIdx.x * 4 + widx;  // 0..2047
  int bh = tid >> 7, i = tid & 127;
  int g = i >> 4;                   // 256-key chunk group
  int base_u = bh * 576 + 8 * g * (g + 1) + (i & 15) * (g + 1);
  int nch = g + 1;
  int row = lane >> 2, d0 = (lane & 3) << 4;
  float M = -3e38f;
  for (int c = 0; c < nch; ++c) {
    const char* pb = partials + (size_t)(base_u + c) * 2176;
    M = fmaxf(M, ((const float*)(pb + 2048))[row]);
  }
  float acc[16];
#pragma unroll
  for (int j = 0; j < 16; ++j) acc[j] = 0.f;
  float lsum = 0.f;
  for (int c = 0; c < nch; ++c) {
    const char* pb = partials + (size_t)(base_u + c) * 2176;
    float mc = ((const float*)(pb + 2048))[row];
    float lc = ((const float*)(pb + 2112))[row];
    float s = __expf(mc - M);
    lsum += s * lc;
    short8 v0 = *reinterpret_cast<const short8*>(pb + row * 128 + d0 * 2);
    short8 v1 = *reinterpret_cast<const short8*>(pb + row * 128 + d0 * 2 + 16);
#pragma unroll
    for (int j = 0; j < 8; ++j) {
      acc[j]     += s * bf2f((unsigned short)v0[j]);
      acc[8 + j] += s * bf2f((unsigned short)v1[j]);
    }
  }
  float inv = 1.f / lsum;
  int b = bh >> 3, h = bh & 7;
  unsigned short* dst = attT + ((size_t)(b * LSEQ) + i * 16 + row) * DIM + h * HS + d0;
  union { unsigned short us[16]; short8 s8[2]; } ou;
#pragma unroll
  for (int j = 0; j < 16; ++j) ou.us[j] = f2bf(acc[j] * inv);
  *reinterpret_cast<short8*>(dst) = ou.s8[0];
  *reinterpret_cast<short8*>(dst + 8) = ou.s8[1];
}

// ---------------- output projection: attT @ wo^T + bo -> fp32 ----------------
__global__ __launch_bounds__(256) void out_kernel(const unsigned short* __restrict__ attT,
    const unsigned short* __restrict__ wob, const float* __restrict__ bo,
    float* __restrict__ out) {
  int lane = threadIdx.x & 63, widx = threadIdx.x >> 6;
  int col = lane & 15, grp = lane >> 4;
  int wgid = blockIdx.x * 4 + widx;  // 0..2047
  int m0 = (wgid >> 3) * 16;
  int n0 = (wgid & 7) * 64;
  f32x4 acc[4];
#pragma unroll
  for (int i = 0; i < 4; ++i) acc[i] = (f32x4){0.f, 0.f, 0.f, 0.f};
  for (int k0 = 0; k0 < DIM; k0 += 32) {
    short8 af = ld8(attT + (size_t)(m0 + col) * DIM + k0 + 8 * grp);
#pragma unroll
    for (int nt = 0; nt < 4; ++nt) {
      short8 bf = ld8(wob + (size_t)(n0 + nt * 16 + col) * DIM + k0 + 8 * grp);
      acc[nt] = mfma_bf16(af, bf, acc[nt]);
    }
  }
#pragma unroll
  for (int nt = 0; nt < 4; ++nt) {
    int n = n0 + nt * 16 + col;
    float bsv = bo[n];
#pragma unroll
    for (int r = 0; r < 4; ++r) {
      int m = m0 + 4 * grp + r;
      out[(size_t)m * DIM + n] = acc[nt][r] + bsv;
    }
  }
}

extern "C" void kernel_launch(void* const* d_in, const int* in_sizes, int n_in,
                              void* d_out, int out_size, void* d_ws, size_t ws_size,
                              hipStream_t stream) {
  const float* x    = (const float*)d_in[0];
  // d_in[1] = mask (causal triu, hardcoded)
  const float* ln_g = (const float*)d_in[2];
  const float* ln_b = (const float*)d_in[3];
  const float* wq   = (const float*)d_in[4];
  const float* bq   = (const float*)d_in[5];
  const float* wk   = (const float*)d_in[6];
  const float* bk   = (const float*)d_in[7];
  const float* wv   = (const float*)d_in[8];
  const float* bv   = (const float*)d_in[9];
  const float* wo   = (const float*)d_in[10];
  const float* bo   = (const float*)d_in[11];
  const float* Er   = (const float*)d_in[12];
  float* out = (float*)d_out;

  char* ws = (char*)d_ws;
  unsigned short* hn   = (unsigned short*)(ws);                    // 0..4 MiB
  unsigned short* qb   = (unsigned short*)(ws + (4u << 20));       // 4..8
  unsigned short* kb   = (unsigned short*)(ws + (8u << 20));       // 8..12
  unsigned short* vT   = (unsigned short*)(ws + (12u << 20));      // 12..16
  unsigned short* erb  = (unsigned short*)(ws + (16u << 20));      // 16..18
  unsigned short* attT = (unsigned short*)(ws + (18u << 20));      // 18..22
  unsigned short* wqb  = (unsigned short*)(ws + (22u << 20));      // 22..24
  unsigned short* wkb  = wqb + 512 * 512;
  unsigned short* wvb  = wkb + 512 * 512;
  unsigned short* wob  = wvb + 512 * 512;
  char* partials       = ws + (24u << 20);                         // 24..~44.1 MiB

  cvt_all_kernel<<<2048, 256, 0, stream>>>(wq, wk, wv, wo, Er, wqb, wkb, wvb, wob, erb);
  ln_kernel<<<4096, 256, 0, stream>>>(x, ln_g, ln_b, hn);
  qkv_kernel<<<1536, 256, 0, stream>>>(hn, wqb, wkb, wvb, bq, bk, bv, qb, kb, vT);
  attn_kernel<<<9216, 256, 0, stream>>>(qb, kb, vT, erb, partials);
  merge_kernel<<<512, 256, 0, stream>>>(partials, attT);
  out_kernel<<<512, 256, 0, stream>>>(attT, wob, bo, out);
}